// Round 5
// baseline (1446.958 us; speedup 1.0000x reference)
//
#include <hip/hip_runtime.h>
#include <stdint.h>

typedef unsigned short u16;
typedef __bf16 bf16x8 __attribute__((ext_vector_type(8)));
typedef float f32x4 __attribute__((ext_vector_type(4)));

#define B_    2
#define C_    256
#define N_    40962
#define BN_   (B_ * N_)          // 81924
#define H_    8
#define HD_   32
#define NTOP  2562
#define TOPW  16
#define NDOWN 2562
#define DOWNW 19
#define M_    (NTOP*TOPW + NDOWN*DOWNW)   // 89670
#define SCALE_ 0.17677669529663687f       // 32^-0.5
#define BN_EPS 1e-5f

// ---------- bf16 helpers (raw u16 storage) ----------
__device__ __forceinline__ float b2f(u16 u) {
    union { uint32_t i; float f; } v; v.i = ((uint32_t)u) << 16; return v.f;
}
__device__ __forceinline__ u16 f2b(float f) {
    union { float f; uint32_t i; } v; v.f = f;
    uint32_t r = v.i + 0x7fffu + ((v.i >> 16) & 1u);   // RNE
    return (u16)(r >> 16);
}
__device__ __forceinline__ float ld(const void* p, size_t i, int isf32) {
    return isf32 ? ((const float*)p)[i] : b2f(((const u16*)p)[i]);
}

// ---------- dtype probe: even u16 indices are garbage iff data is f32 ----------
__global__ void probe_k(const void* __restrict__ x, int* __restrict__ flag) {
    int lane = threadIdx.x;
    u16 v = ((const u16*)x)[2 * lane];
    int e = (v >> 7) & 0xff;
    bool ok = (e >= 118 && e <= 134);
    unsigned long long m = __ballot(ok);
    if (lane == 0) *flag = (__popcll(m) < 32) ? 1 : 0;   // 1 = f32 inputs
}

// ---------- weight prep: transposed (k-contiguous) bf16 weights ----------
// WcatT: (1024 n) x (256 k); WprojT: (256 n) x (256 k)
__global__ void wprep_k(const void* __restrict__ Wqkv, const void* __restrict__ Wres,
                        const void* __restrict__ Wproj,
                        u16* __restrict__ WcatT, u16* __restrict__ WprojT,
                        const int* __restrict__ flag) {
    const int f = *flag;
    int k = blockIdx.x, t = threadIdx.x;
    for (int j = t; j < 768; j += 256) WcatT[(size_t)j * 256 + k] = f2b(ld(Wqkv, (size_t)k * 768 + j, f));
    WcatT[(size_t)(768 + t) * 256 + k] = f2b(ld(Wres, (size_t)k * 256 + t, f));
    WprojT[(size_t)t * 256 + k] = f2b(ld(Wproj, (size_t)k * 256 + t, f));
}

__global__ void biasprep_k(const void* bqkv, const void* bres, const void* bproj,
                           float* bias_cat, float* bias_proj, const int* __restrict__ flag) {
    const int f = *flag;
    int g = blockIdx.x * 256 + threadIdx.x;
    if (g < 768) bias_cat[g] = ld(bqkv, g, f);
    else if (g < 1024) bias_cat[g] = ld(bres, g - 768, f);
    else if (g < 1280) bias_proj[g - 1024] = ld(bproj, g - 1024, f);
}

// WfT[n][k] = (Wm1 @ Wm2)[k][n]   (256x512 @ 512x256), bf16, transposed out
__global__ __launch_bounds__(256) void wf_k(const void* __restrict__ Wm1, const void* __restrict__ Wm2,
                                            u16* __restrict__ WfT, const int* __restrict__ flag) {
    const int f = *flag;
    __shared__ float row[512];
    int i = blockIdx.x, t = threadIdx.x;   // i = k index (row of Wm1)
    row[t] = ld(Wm1, (size_t)i * 512 + t, f);
    row[t + 256] = ld(Wm1, (size_t)i * 512 + 256 + t, f);
    __syncthreads();
    float acc = 0.f;
    for (int k = 0; k < 512; ++k) acc += row[k] * ld(Wm2, (size_t)k * 256 + t, f);
    WfT[(size_t)t * 256 + i] = f2b(acc);
}

// bf = bm1 @ Wm2 + bm2   (f32)
__global__ void bf_k(const void* bm1, const void* __restrict__ Wm2, const void* bm2,
                     float* bf, const int* __restrict__ flag) {
    const int f = *flag;
    int t = threadIdx.x;
    float acc = ld(bm2, t, f);
    for (int k = 0; k < 512; ++k) acc += ld(bm1, k, f) * ld(Wm2, (size_t)k * 256 + t, f);
    bf[t] = acc;
}

// ---------- transpose+convert: x (B,C,N) f32/bf16 -> xt (B*N, 256) bf16 ----------
__global__ __launch_bounds__(256) void txin_k(const void* __restrict__ x, u16* __restrict__ xt,
                                              const int* __restrict__ flag) {
    const int f = *flag;
    __shared__ __align__(16) float tile[64][65];
    const int n0 = blockIdx.x * 64, c0 = blockIdx.y * 64, b = blockIdx.z;
    const int tid = threadIdx.x;
    {
        const int lc = tid >> 2, ns = (tid & 3) * 16;
        size_t base = ((size_t)(b * C_ + c0 + lc)) * N_ + n0 + ns;
#pragma unroll
        for (int j = 0; j < 16; ++j) {
            int n = n0 + ns + j;
            tile[lc][ns + j] = (n < N_) ? ld(x, base + j, f) : 0.f;
        }
    }
    __syncthreads();
    {
        const int ln = tid >> 2, cs = (tid & 3) * 16;
        int n = n0 + ln;
        if (n < N_) {
            size_t base = ((size_t)(b * N_ + n)) * 256 + c0 + cs;
#pragma unroll
            for (int j = 0; j < 16; j += 2) {
                uint32_t v = (uint32_t)f2b(tile[cs + j][ln]) | ((uint32_t)f2b(tile[cs + j + 1][ln]) << 16);
                *reinterpret_cast<uint32_t*>(xt + base + j) = v;
            }
        }
    }
}

// ---------- wide MFMA GEMM: Out(Rtot x *) tile 64x256 per block ----------
// A (Rtot x 256) bf16 row-major ld=ldA; BT (ncols x 256) bf16 k-contiguous rows.
template<bool ADD_RES, bool OUT_F32>
__global__ __launch_bounds__(256) void gemm_wide_k(
    const u16* __restrict__ A, int ldA, const u16* __restrict__ BT,
    const float* __restrict__ bias,
    const u16* __restrict__ resp, int ldRes,
    void* __restrict__ Out, int ldOut, int Rtot)
{
    __shared__ __align__(16) u16 As[64][40];
    __shared__ __align__(16) u16 Bs[256][40];
    const int tid = threadIdx.x;
    const int R0 = blockIdx.x * 64;
    const int C0 = blockIdx.y * 256;
    const int wave = tid >> 6, lane = tid & 63;
    const int quad = lane >> 4, mrow = lane & 15;
    const int ar = tid >> 2, ak8 = (tid & 3) * 8;

    f32x4 acc[4][4];
#pragma unroll
    for (int mt = 0; mt < 4; ++mt)
#pragma unroll
        for (int nt = 0; nt < 4; ++nt) acc[mt][nt] = f32x4{0, 0, 0, 0};

    for (int k0 = 0; k0 < 256; k0 += 32) {
        uint4 av = make_uint4(0u, 0u, 0u, 0u);
        const int grow = R0 + ar;
        if (grow < Rtot)
            av = *reinterpret_cast<const uint4*>(A + (size_t)grow * ldA + k0 + ak8);
        uint4 bv[4];
#pragma unroll
        for (int s = 0; s < 4; ++s)
            bv[s] = *reinterpret_cast<const uint4*>(BT + (size_t)(C0 + ar + 64 * s) * 256 + k0 + ak8);
        __syncthreads();
        *reinterpret_cast<uint4*>(&As[ar][ak8]) = av;
#pragma unroll
        for (int s = 0; s < 4; ++s)
            *reinterpret_cast<uint4*>(&Bs[ar + 64 * s][ak8]) = bv[s];
        __syncthreads();
        bf16x8 afrag[4], bfrag[4];
#pragma unroll
        for (int mt = 0; mt < 4; ++mt)
            afrag[mt] = *reinterpret_cast<const bf16x8*>(&As[mt * 16 + mrow][quad * 8]);
#pragma unroll
        for (int nt = 0; nt < 4; ++nt)
            bfrag[nt] = *reinterpret_cast<const bf16x8*>(&Bs[wave * 64 + nt * 16 + mrow][quad * 8]);
#pragma unroll
        for (int mt = 0; mt < 4; ++mt)
#pragma unroll
            for (int nt = 0; nt < 4; ++nt)
                acc[mt][nt] = __builtin_amdgcn_mfma_f32_16x16x32_bf16(afrag[mt], bfrag[nt], acc[mt][nt], 0, 0, 0);
    }

#pragma unroll
    for (int nt = 0; nt < 4; ++nt) {
        const int col = C0 + wave * 64 + nt * 16 + mrow;
        const float bcol = bias[col];
#pragma unroll
        for (int mt = 0; mt < 4; ++mt) {
#pragma unroll
            for (int r = 0; r < 4; ++r) {
                int row = R0 + mt * 16 + quad * 4 + r;
                if (row < Rtot) {
                    float v = acc[mt][nt][r] + bcol;
                    if (ADD_RES) v += b2f(resp[(size_t)row * ldRes + col]);
                    if (OUT_F32) ((float*)Out)[(size_t)row * ldOut + col] = v;
                    else         ((u16*)Out)[(size_t)row * ldOut + col] = f2b(v);
                }
            }
        }
    }
}

// ---------- window attention: one block per (window, batch), all 8 heads ----------
// qkvres: (B*N, 1024) bf16 [q|k|v|res]; xw: (B, M_+1, 256) bf16
template<int W>
__global__ __launch_bounds__(256) void attn_k(const u16* __restrict__ qkv, const int* __restrict__ widx,
                                              u16* __restrict__ xw, int mbase)
{
    const int w = blockIdx.x, b = blockIdx.y;
    const int tid = threadIdx.x;
    __shared__ int wi[W];
    __shared__ __align__(16) float Qf[W][260];
    __shared__ __align__(16) u16 Kb[W][264];
    __shared__ __align__(16) u16 Vb[W][264];
    __shared__ __align__(16) float P[8][W][W + 1];
    if (tid < W) wi[tid] = widx[w * W + tid];
    __syncthreads();
    for (int e = tid; e < W * 256; e += 256) {
        int j = e >> 8, c = e & 255;
        size_t base = ((size_t)(b * N_ + wi[j])) * 1024 + c;
        Qf[j][c] = b2f(qkv[base]) * SCALE_;
        Kb[j][c] = qkv[base + 256];
        Vb[j][c] = qkv[base + 512];
    }
    __syncthreads();
    for (int e = tid; e < 8 * W * W; e += 256) {
        int h = e / (W * W); int rem = e - h * W * W; int j = rem / W, jj = rem - j * W;
        const float* qp = &Qf[j][h * 32];
        const u16* kp = &Kb[jj][h * 32];
        float s = 0.f;
#pragma unroll
        for (int c = 0; c < 32; ++c) s += qp[c] * b2f(kp[c]);
        P[h][j][jj] = s;
    }
    __syncthreads();
    for (int e = tid; e < 8 * W; e += 256) {
        int h = e / W, j = e - h * W;
        float m = -1e30f;
        for (int jj = 0; jj < W; ++jj) m = fmaxf(m, P[h][j][jj]);
        float tmp[W];
        float sum = 0.f;
        for (int jj = 0; jj < W; ++jj) { tmp[jj] = __expf(P[h][j][jj] - m); sum += tmp[jj]; }
        float inv = 1.0f / sum;
        for (int jj = 0; jj < W; ++jj) P[h][j][jj] = tmp[jj] * inv;
    }
    __syncthreads();
    for (int e = tid; e < W * 64; e += 256) {
        int j = e >> 6, ch = e & 63;           // col = ch*4
        int h = ch >> 3;
        float a0 = 0, a1 = 0, a2 = 0, a3 = 0;
        for (int jj = 0; jj < W; ++jj) {
            float p = P[h][j][jj];
            const u16* vp = &Vb[jj][ch * 4];
            a0 += p * b2f(vp[0]); a1 += p * b2f(vp[1]); a2 += p * b2f(vp[2]); a3 += p * b2f(vp[3]);
        }
        int m = mbase + w * W + j;
        size_t o = ((size_t)b * (M_ + 1) + m) * 256 + ch * 4;
        ushort4 st;
        st.x = f2b(a0); st.y = f2b(a1); st.z = f2b(a2); st.w = f2b(a3);
        *reinterpret_cast<ushort4*>(xw + o) = st;
    }
}

// ---------- gather + average -> xf written into qkvres cols 0..255 (ld 1024) ----------
__global__ __launch_bounds__(256) void gather_k(const u16* __restrict__ xw, const int* __restrict__ rev,
                                                const void* __restrict__ cnt_inv, u16* __restrict__ xfp,
                                                int K, const int* __restrict__ flag)
{
    const int f = *flag;
    int gid = blockIdx.x * 4 + (threadIdx.x >> 6);
    if (gid >= BN_) return;
    int b = (gid >= N_) ? 1 : 0;
    int n = gid - b * N_;
    int c4 = (threadIdx.x & 63) * 4;
    float a0 = 0, a1 = 0, a2 = 0, a3 = 0;
    const int* rp = rev + (size_t)n * K;
    for (int k = 0; k < K; ++k) {
        int idx = rp[k];
        if (idx < M_) {
            ushort4 v = *reinterpret_cast<const ushort4*>(xw + ((size_t)b * (M_ + 1) + idx) * 256 + c4);
            a0 += b2f(v.x); a1 += b2f(v.y); a2 += b2f(v.z); a3 += b2f(v.w);
        }
    }
    float ci = ld(cnt_inv, n, f);
    ushort4 o;
    o.x = f2b(a0 * ci); o.y = f2b(a1 * ci); o.z = f2b(a2 * ci); o.w = f2b(a3 * ci);
    *reinterpret_cast<ushort4*>(xfp + (size_t)gid * 1024 + c4) = o;
}

// ---------- BN stats over res2 (BN_ x 256 f32) ----------
__global__ __launch_bounds__(256) void stats_k(const float* __restrict__ res2, float* __restrict__ sums) {
    int c = threadIdx.x;
    int r0 = blockIdx.x * 1281;
    int r1 = r0 + 1281; if (r1 > BN_) r1 = BN_;
    float s = 0.f, s2 = 0.f;
    for (int r = r0; r < r1; ++r) {
        float v = res2[(size_t)r * 256 + c];
        s += v; s2 += v * v;
    }
    atomicAdd(&sums[c], s);
    atomicAdd(&sums[256 + c], s2);
}

__global__ void bnfin_k(const float* sums, const void* gamma, const void* beta, float* ss,
                        const int* __restrict__ flag) {
    const int f = *flag;
    int c = threadIdx.x;
    float mean = sums[c] * (1.0f / BN_);
    float var = sums[256 + c] * (1.0f / BN_) - mean * mean;
    float inv = rsqrtf(fmaxf(var, 0.f) + BN_EPS);
    float sc = ld(gamma, c, f) * inv;
    ss[c] = sc;
    ss[256 + c] = ld(beta, c, f) - mean * sc;
}

// ---------- final: y[b,oc,n] = out[b,n,oc] + res2[b,n,oc]*scale[oc] + shift[oc] ----------
__global__ __launch_bounds__(256) void final_k(const u16* __restrict__ outb, const float* __restrict__ res2,
                                               const float* __restrict__ ss, void* __restrict__ y,
                                               const int* __restrict__ flag)
{
    const int isf32 = *flag;
    __shared__ __align__(16) float tile[64][65];
    const int n0 = blockIdx.x * 64, o0 = blockIdx.y * 64, b = blockIdx.z;
    const int tid = threadIdx.x;
    {
        const int ln = tid >> 2, os = (tid & 3) * 16;
        int n = n0 + ln;
        if (n < N_) {
            size_t base = ((size_t)(b * N_ + n)) * 256 + o0 + os;
#pragma unroll
            for (int j = 0; j < 16; ++j) {
                int oc = o0 + os + j;
                tile[ln][os + j] = b2f(outb[base + j]) + res2[base + j] * ss[oc] + ss[256 + oc];
            }
        }
    }
    __syncthreads();
    {
        const int lo = tid >> 2, nsg = (tid & 3) * 16;
        int oc = o0 + lo;
        size_t ybase = ((size_t)(b * 256 + oc)) * N_ + n0 + nsg;
        if (isf32) {
            float* yp = (float*)y;
#pragma unroll
            for (int j = 0; j < 16; j += 2) {
                int n2 = n0 + nsg + j;
                if (n2 < N_) {
                    float2 st; st.x = tile[nsg + j][lo]; st.y = tile[nsg + j + 1][lo];
                    *reinterpret_cast<float2*>(yp + ybase + j) = st;
                }
            }
        } else {
            u16* yp = (u16*)y;
#pragma unroll
            for (int j = 0; j < 16; j += 2) {
                int n2 = n0 + nsg + j;
                if (n2 < N_) {
                    uint32_t v = (uint32_t)f2b(tile[nsg + j][lo]) | ((uint32_t)f2b(tile[nsg + j + 1][lo]) << 16);
                    *reinterpret_cast<uint32_t*>(yp + ybase + j) = v;
                }
            }
        }
    }
}

// ---------- workspace layout (bytes) ----------
static const size_t OFF_QKV   = 0;           // qkvres 167.8MB; res2 f32 (84MB) aliases after proj
static const size_t OFF_XW    = 167780352;   // xt (42MB) -> xw (91.8MB) -> outb (42MB)
static const size_t OFF_SMALL = 259603456;

extern "C" void kernel_launch(void* const* d_in, const int* in_sizes, int n_in,
                              void* d_out, int out_size, void* d_ws, size_t ws_size,
                              hipStream_t stream) {
    const void* x     = d_in[0];
    const void* Wqkv  = d_in[1];
    const void* bqkv  = d_in[2];
    const void* Wproj = d_in[3];
    const void* bproj = d_in[4];
    const void* Wres  = d_in[5];
    const void* bres  = d_in[6];
    const void* Wm1   = d_in[7];
    const void* bm1   = d_in[8];
    const void* Wm2   = d_in[9];
    const void* bm2   = d_in[10];
    const void* gamma = d_in[11];
    const void* beta  = d_in[12];
    const void* cnt_inv = d_in[13];
    const int* top_idx = (const int*)d_in[14];
    const int* down_idx = (const int*)d_in[15];
    const int* rev   = (const int*)d_in[16];
    const int K = in_sizes[16] / N_;

    char* ws = (char*)d_ws;
    u16*  qkvres  = (u16*)(ws + OFF_QKV);
    float* res2   = (float*)(ws + OFF_QKV);
    u16*  xt      = (u16*)(ws + OFF_XW);
    u16*  xw      = (u16*)(ws + OFF_XW);
    u16*  outb    = (u16*)(ws + OFF_XW);
    u16*  WcatT   = (u16*)(ws + OFF_SMALL);                 // 524288
    u16*  WprojT  = (u16*)(ws + OFF_SMALL + 524288);        // 131072
    u16*  WfT     = (u16*)(ws + OFF_SMALL + 655360);        // 131072
    float* bias_cat  = (float*)(ws + OFF_SMALL + 786432);   // 4096
    float* bias_proj = (float*)(ws + OFF_SMALL + 790528);   // 4096
    float* bfv       = (float*)(ws + OFF_SMALL + 794624);   // 4096
    float* stats     = (float*)(ws + OFF_SMALL + 798720);   // 4096
    float* ssbuf     = (float*)(ws + OFF_SMALL + 802816);   // 4096
    int*   flag      = (int*)(ws + OFF_SMALL + 806912);

    // dtype probe
    probe_k<<<1, 64, 0, stream>>>(x, flag);

    // prep (dtype-adaptive, transposed weights)
    wprep_k<<<256, 256, 0, stream>>>(Wqkv, Wres, Wproj, WcatT, WprojT, flag);
    biasprep_k<<<5, 256, 0, stream>>>(bqkv, bres, bproj, bias_cat, bias_proj, flag);
    wf_k<<<256, 256, 0, stream>>>(Wm1, Wm2, WfT, flag);
    bf_k<<<1, 256, 0, stream>>>(bm1, Wm2, bm2, bfv, flag);

    // transpose x -> xt (BN,256) bf16
    txin_k<<<dim3(641, 4, 2), 256, 0, stream>>>(x, xt, flag);

    // qkv + res fused GEMM: (BN,256) @ (256,1024), 64x256 tiles
    gemm_wide_k<false, false><<<dim3(1281, 4), 256, 0, stream>>>(
        xt, 256, WcatT, bias_cat, nullptr, 0, (void*)qkvres, 1024, BN_);

    // window attention (all heads per block)
    attn_k<TOPW><<<dim3(NTOP, B_), 256, 0, stream>>>(qkvres, top_idx, xw, 0);
    attn_k<DOWNW><<<dim3(NDOWN, B_), 256, 0, stream>>>(qkvres, down_idx, xw, NTOP * TOPW);

    // scatter-average back to points -> xf = qkvres cols 0..255 (q is dead)
    gather_k<<<(BN_ + 3) / 4, 256, 0, stream>>>(xw, rev, cnt_inv, qkvres, K, flag);

    // out = xf @ Wproj + bproj + res
    gemm_wide_k<true, false><<<dim3(1281, 1), 256, 0, stream>>>(
        qkvres, 1024, WprojT, bias_proj, qkvres + 768, 1024, (void*)outb, 256, BN_);

    // res2 = out @ (Wm1@Wm2) + (bm1@Wm2+bm2)   (f32, overwrites dead qkvres front)
    gemm_wide_k<false, true><<<dim3(1281, 1), 256, 0, stream>>>(
        outb, 256, WfT, bfv, nullptr, 0, (void*)res2, 256, BN_);

    // batchnorm stats + finalize
    (void)hipMemsetAsync(stats, 0, 512 * sizeof(float), stream);
    stats_k<<<64, 256, 0, stream>>>(res2, stats);
    bnfin_k<<<1, 256, 0, stream>>>(stats, gamma, beta, ssbuf, flag);

    // fused transpose + BN + residual add -> y (B, 256, N)
    final_k<<<dim3(641, 4, 2), 256, 0, stream>>>(outb, res2, ssbuf, d_out, flag);
}